// Round 1
// baseline (834.300 us; speedup 1.0000x reference)
//
#include <hip/hip_runtime.h>
#include <hip/hip_bf16.h>

#define N_NODES 100000
#define N_EDGES 1200000
#define D 64

// ---------------------------------------------------------------------------
// Kernel 1: edge scatter. One 64-lane wave per edge (grid-stride).
// lane d: agg[dst][d] += feat[src][d]; lane 0: deg[dst] += 1.
// ---------------------------------------------------------------------------
__global__ __launch_bounds__(256) void sage_scatter(
    const float* __restrict__ feat,
    const int*   __restrict__ src,
    const int*   __restrict__ dst,
    float*       __restrict__ agg,
    float*       __restrict__ deg,
    int nEdges)
{
    const int lane   = threadIdx.x & 63;
    const int waveId = (blockIdx.x * blockDim.x + threadIdx.x) >> 6;
    const int nWaves = (gridDim.x * blockDim.x) >> 6;

    for (int e = waveId; e < nEdges; e += nWaves) {
        const int s = src[e];
        const int d = dst[e];
        const float v = feat[(size_t)s * D + lane];
        atomicAdd(&agg[(size_t)d * D + lane], v);
        if (lane == 0) atomicAdd(&deg[d], 1.0f);
    }
}

// ---------------------------------------------------------------------------
// Kernel 2: per-node transform.
// out[n][d] = b[d] + sum_k feat[n][k]*Ws[d][k] + (agg[n][k]/max(deg,1))*Wn[d][k]
// W matrices staged transposed in LDS so lane-indexed reads are consecutive
// (conflict-free: 2 lanes/bank). Row values broadcast via __shfl.
// ---------------------------------------------------------------------------
__global__ __launch_bounds__(256) void sage_transform(
    const float* __restrict__ feat,
    const float* __restrict__ agg,
    const float* __restrict__ deg,
    const float* __restrict__ Ws,
    const float* __restrict__ Wn,
    const float* __restrict__ bias,
    float*       __restrict__ out,
    int nNodes)
{
    __shared__ float WsT[D][D];   // WsT[k][d] = Ws[d][k]
    __shared__ float WnT[D][D];

    for (int i = threadIdx.x; i < D * D; i += blockDim.x) {
        const int d = i >> 6, k = i & 63;
        WsT[k][d] = Ws[i];
        WnT[k][d] = Wn[i];
    }
    __syncthreads();

    const int lane = threadIdx.x & 63;
    const int wave = threadIdx.x >> 6;                 // 4 waves/block
    const int node = blockIdx.x * 4 + wave;
    const float bv = bias[lane];

    if (node >= nNodes) return;

    const float f = feat[(size_t)node * D + lane];
    const float a = agg [(size_t)node * D + lane];
    const float inv = 1.0f / fmaxf(deg[node], 1.0f);

    float accS = bv;
    float accN = 0.0f;
#pragma unroll
    for (int k = 0; k < D; ++k) {
        const float fk = __shfl(f, k, 64);
        const float ak = __shfl(a, k, 64);
        accS = fmaf(fk, WsT[k][lane], accS);
        accN = fmaf(ak, WnT[k][lane], accN);
    }
    out[(size_t)node * D + lane] = accS + accN * inv;
}

// ---------------------------------------------------------------------------
extern "C" void kernel_launch(void* const* d_in, const int* in_sizes, int n_in,
                              void* d_out, int out_size, void* d_ws, size_t ws_size,
                              hipStream_t stream)
{
    const float* feat = (const float*)d_in[0];
    const int*   src  = (const int*)  d_in[1];
    const int*   dst  = (const int*)  d_in[2];
    const float* Ws   = (const float*)d_in[3];
    const float* Wn   = (const float*)d_in[4];
    const float* bias = (const float*)d_in[5];
    float*       out  = (float*)d_out;

    const int nEdges = in_sizes[1];
    const int nNodes = in_sizes[0] / D;

    float* agg = (float*)d_ws;                      // [N_NODES * D]
    float* deg = agg + (size_t)nNodes * D;          // [N_NODES]

    // zero accumulators every call (harness does not re-poison between replays)
    hipMemsetAsync(agg, 0, ((size_t)nNodes * D + nNodes) * sizeof(float), stream);

    // scatter: 4096 blocks x 256 threads = 16384 waves, ~74 edges each
    sage_scatter<<<4096, 256, 0, stream>>>(feat, src, dst, agg, deg, nEdges);

    // transform: 4 nodes per block
    const int nBlocks = (nNodes + 3) / 4;
    sage_transform<<<nBlocks, 256, 0, stream>>>(feat, agg, deg, Ws, Wn, bias, out, nNodes);
}

// Round 3
// 394.778 us; speedup vs baseline: 2.1133x; 2.1133x over previous
//
#include <hip/hip_runtime.h>
#include <hip/hip_bf16.h>

#define N_NODES 100000
#define N_EDGES 1200000
#define D 64

// ---------------------------------------------------------------------------
// Kernel 0: zero the agg+deg scratch. Plain kernel node instead of
// hipMemsetAsync: R2's post-timing divergence implicates the captured memset
// node's ordering vs the scatter kernel; kernel->kernel stream edges are
// proven to hold (scatter->transform worked in R1).
// n is a multiple of 4 -> float4 stores.
// ---------------------------------------------------------------------------
__global__ __launch_bounds__(256) void zero_f32(float4* __restrict__ p, int n4)
{
    int i = blockIdx.x * blockDim.x + threadIdx.x;
    const int stride = gridDim.x * blockDim.x;
    const float4 z = make_float4(0.f, 0.f, 0.f, 0.f);
    for (; i < n4; i += stride) p[i] = z;
}

// ---------------------------------------------------------------------------
// Kernel 1: edge scatter. One 64-lane wave per edge (grid-stride).
// lane d: agg[dst][d] += feat[src][d]; lane 0: deg[dst] += 1.
// ---------------------------------------------------------------------------
__global__ __launch_bounds__(256) void sage_scatter(
    const float* __restrict__ feat,
    const int*   __restrict__ src,
    const int*   __restrict__ dst,
    float*       __restrict__ agg,
    float*       __restrict__ deg,
    int nEdges)
{
    const int lane   = threadIdx.x & 63;
    const int waveId = (blockIdx.x * blockDim.x + threadIdx.x) >> 6;
    const int nWaves = (gridDim.x * blockDim.x) >> 6;

    for (int e = waveId; e < nEdges; e += nWaves) {
        const int s = src[e];
        const int d = dst[e];
        const float v = feat[(size_t)s * D + lane];
        atomicAdd(&agg[(size_t)d * D + lane], v);
        if (lane == 0) atomicAdd(&deg[d], 1.0f);
    }
}

// ---------------------------------------------------------------------------
// Kernel 2: per-node transform, register-resident W, zero LDS in inner loop.
// out[n][lane] = b[lane] + sum_k feat[n][k]*Ws[lane][k]
//                        + (agg[n][k]/max(deg,1))*Wn[lane][k]
// Each lane caches its own Ws/Wn row (64+64 f32 VGPRs, statically indexed via
// full unroll). feat[n][k] / agg[n][k] are wave-uniform per k: broadcast with
// v_readlane (VALU, no LDS) instead of ds_bpermute. Inner loop = 2 readlane +
// 2 FMA per k. R2's transform was LDS-instr-throughput-bound (~210us).
// ---------------------------------------------------------------------------
__global__ __launch_bounds__(256) void sage_transform_reg(
    const float* __restrict__ feat,
    const float* __restrict__ agg,
    const float* __restrict__ deg,
    const float* __restrict__ Ws,
    const float* __restrict__ Wn,
    const float* __restrict__ bias,
    float*       __restrict__ out,
    int nNodes)
{
    const int lane = threadIdx.x & 63;
    const int wid  = (blockIdx.x * blockDim.x + threadIdx.x) >> 6;
    const int nW   = (gridDim.x * blockDim.x) >> 6;

    // per-lane W rows: lane d holds Ws[d][0..63], Wn[d][0..63]
    float ws[D], wn[D];
#pragma unroll
    for (int k = 0; k < D; ++k) {
        ws[k] = Ws[lane * D + k];   // gather, L1/L2-served after first wave
        wn[k] = Wn[lane * D + k];
    }
    const float bv = bias[lane];

    for (int n = wid; n < nNodes; n += nW) {
        const float f = feat[(size_t)n * D + lane];
        const float a = agg [(size_t)n * D + lane];
        const float inv = 1.0f / fmaxf(deg[n], 1.0f);

        float accS = bv;
        float accN = 0.0f;
#pragma unroll
        for (int k = 0; k < D; ++k) {
            const float fk = __uint_as_float(
                __builtin_amdgcn_readlane(__float_as_uint(f), k));
            const float ak = __uint_as_float(
                __builtin_amdgcn_readlane(__float_as_uint(a), k));
            accS = fmaf(fk, ws[k], accS);
            accN = fmaf(ak, wn[k], accN);
        }
        out[(size_t)n * D + lane] = accS + accN * inv;
    }
}

// ---------------------------------------------------------------------------
extern "C" void kernel_launch(void* const* d_in, const int* in_sizes, int n_in,
                              void* d_out, int out_size, void* d_ws, size_t ws_size,
                              hipStream_t stream)
{
    const float* feat = (const float*)d_in[0];
    const int*   src  = (const int*)  d_in[1];
    const int*   dst  = (const int*)  d_in[2];
    const float* Ws   = (const float*)d_in[3];
    const float* Wn   = (const float*)d_in[4];
    const float* bias = (const float*)d_in[5];
    float*       out  = (float*)d_out;

    const int nEdges = in_sizes[1];
    const int nNodes = in_sizes[0] / D;

    float* agg = (float*)d_ws;                      // [N_NODES * D]
    float* deg = agg + (size_t)nNodes * D;          // [N_NODES]

    // zero accumulators every call (kernel node, not memset node)
    const int nZero4 = (nNodes * D + nNodes) / 4;   // 6.5M floats, mult of 4
    zero_f32<<<2048, 256, 0, stream>>>((float4*)d_ws, nZero4);

    // scatter: 4096 blocks x 256 threads = 16384 waves, ~74 edges each
    sage_scatter<<<4096, 256, 0, stream>>>(feat, src, dst, agg, deg, nEdges);

    // transform: 2048 blocks -> 8192 waves, ~12 nodes each
    sage_transform_reg<<<2048, 256, 0, stream>>>(feat, agg, deg, Ws, Wn, bias,
                                                 out, nNodes);
}

// Round 4
// 293.626 us; speedup vs baseline: 2.8414x; 1.3445x over previous
//
#include <hip/hip_runtime.h>

#define D 64
#define SCAN_B 1024

// ---------------------------------------------------------------------------
// CSR-by-dst pipeline. R3 counters showed the atomic scatter writes 337 MB /
// fetches 170 MB HBM per call (L2 thrash on 76.8M random f32 atomics). This
// pipeline does 2.4M int atomics on L2-resident arrays instead, then a
// deterministic-order gather-sum per node.
// ---------------------------------------------------------------------------

__global__ __launch_bounds__(256) void k_zero_i32(int* __restrict__ p, int n)
{
    int i = blockIdx.x * blockDim.x + threadIdx.x;
    const int st = gridDim.x * blockDim.x;
    for (; i < n; i += st) p[i] = 0;
}

__global__ __launch_bounds__(256) void k_hist(
    const int* __restrict__ dst, int* __restrict__ deg, int e)
{
    int i = blockIdx.x * blockDim.x + threadIdx.x;
    const int st = gridDim.x * blockDim.x;
    for (; i < e; i += st) atomicAdd(&deg[dst[i]], 1);
}

// per-block exclusive scan of deg -> rowptr (local), block total -> bsum
__global__ __launch_bounds__(SCAN_B) void k_scan1(
    const int* __restrict__ deg, int* __restrict__ rowptr,
    int* __restrict__ bsum, int n)
{
    __shared__ int s[SCAN_B];
    const int t = threadIdx.x;
    const int g = blockIdx.x * SCAN_B + t;
    const int v = (g < n) ? deg[g] : 0;
    s[t] = v;
    __syncthreads();
    for (int off = 1; off < SCAN_B; off <<= 1) {
        const int u = (t >= off) ? s[t - off] : 0;
        __syncthreads();
        s[t] += u;
        __syncthreads();
    }
    if (g < n) rowptr[g] = s[t] - v;                 // exclusive
    if (t == SCAN_B - 1) bsum[blockIdx.x] = s[t];    // inclusive block total
}

// single block: exclusive scan of <=128 block totals in place
__global__ __launch_bounds__(128) void k_scan2(int* __restrict__ bsum, int nb)
{
    __shared__ int s[128];
    const int t = threadIdx.x;
    const int v = (t < nb) ? bsum[t] : 0;
    s[t] = v;
    __syncthreads();
    for (int off = 1; off < 128; off <<= 1) {
        const int u = (t >= off) ? s[t - off] : 0;
        __syncthreads();
        s[t] += u;
        __syncthreads();
    }
    if (t < nb) bsum[t] = s[t] - v;
}

// rowptr += block offset; cursor = rowptr; rowptr[n] = e
__global__ __launch_bounds__(256) void k_scan3(
    int* __restrict__ rowptr, const int* __restrict__ bsum,
    int* __restrict__ cursor, int n, int e)
{
    const int g = blockIdx.x * blockDim.x + threadIdx.x;
    if (g < n) {
        const int r = rowptr[g] + bsum[g >> 10];     // SCAN_B = 1024
        rowptr[g] = r;
        cursor[g] = r;
    }
    if (g == 0) rowptr[n] = e;
}

__global__ __launch_bounds__(256) void k_fill(
    const int* __restrict__ src, const int* __restrict__ dst,
    int* __restrict__ cursor, int* __restrict__ eidx, int e)
{
    int i = blockIdx.x * blockDim.x + threadIdx.x;
    const int st = gridDim.x * blockDim.x;
    for (; i < e; i += st) {
        const int p = atomicAdd(&cursor[dst[i]], 1);
        eidx[p] = src[i];
    }
}

// one wave per node: gather feat rows of in-neighbors, mean into hmean (=d_out)
__global__ __launch_bounds__(256) void k_agg_mean(
    const float* __restrict__ feat, const int* __restrict__ rowptr,
    const int* __restrict__ eidx, float* __restrict__ hmean, int nNodes)
{
    const int lane = threadIdx.x & 63;
    const int wid  = (blockIdx.x * blockDim.x + threadIdx.x) >> 6;
    const int nW   = (gridDim.x * blockDim.x) >> 6;

    for (int n = wid; n < nNodes; n += nW) {
        const int beg = rowptr[n], end = rowptr[n + 1];
        float acc = 0.f;
        for (int base = beg; base < end; base += 64) {
            const int m = min(64, end - base);
            const int sv = (lane < m) ? eidx[base + lane] : 0;  // coalesced
#pragma unroll 4
            for (int j = 0; j < m; ++j) {
                const int s = __builtin_amdgcn_readlane(sv, j);
                acc += feat[(size_t)s * D + lane];              // coalesced 256B
            }
        }
        const float inv = 1.f / fmaxf((float)(end - beg), 1.f);
        hmean[(size_t)n * D + lane] = acc * inv;
    }
}

// register-W transform (proven in R3). Reads h from out, overwrites out in
// place: all readlanes of h precede the write within each wave; rows are
// wave-exclusive.
__global__ __launch_bounds__(256) void k_transform(
    const float* __restrict__ feat,
    const float* __restrict__ Ws, const float* __restrict__ Wn,
    const float* __restrict__ bias,
    float* out, int nNodes)
{
    const int lane = threadIdx.x & 63;
    const int wid  = (blockIdx.x * blockDim.x + threadIdx.x) >> 6;
    const int nW   = (gridDim.x * blockDim.x) >> 6;

    float ws[D], wn[D];
#pragma unroll
    for (int k = 0; k < D; ++k) {
        ws[k] = Ws[lane * D + k];
        wn[k] = Wn[lane * D + k];
    }
    const float bv = bias[lane];

    for (int n = wid; n < nNodes; n += nW) {
        const float f = feat[(size_t)n * D + lane];
        const float h = out[(size_t)n * D + lane];   // mean already applied
        float accS = bv;
        float accN = 0.f;
#pragma unroll
        for (int k = 0; k < D; ++k) {
            const float fk = __uint_as_float(
                __builtin_amdgcn_readlane(__float_as_uint(f), k));
            const float hk = __uint_as_float(
                __builtin_amdgcn_readlane(__float_as_uint(h), k));
            accS = fmaf(fk, ws[k], accS);
            accN = fmaf(hk, wn[k], accN);
        }
        out[(size_t)n * D + lane] = accS + accN;
    }
}

// ---------------------------------------------------------------------------
extern "C" void kernel_launch(void* const* d_in, const int* in_sizes, int n_in,
                              void* d_out, int out_size, void* d_ws, size_t ws_size,
                              hipStream_t stream)
{
    const float* feat = (const float*)d_in[0];
    const int*   src  = (const int*)  d_in[1];
    const int*   dst  = (const int*)  d_in[2];
    const float* Ws   = (const float*)d_in[3];
    const float* Wn   = (const float*)d_in[4];
    const float* bias = (const float*)d_in[5];
    float*       out  = (float*)d_out;

    const int nEdges = in_sizes[1];
    const int nNodes = in_sizes[0] / D;
    const int NB     = (nNodes + SCAN_B - 1) / SCAN_B;   // 98 (<=128 for scan2)

    // ws layout (all int32): ~6.0 MB total
    int* deg    = (int*)d_ws;            // [nNodes]
    int* rowptr = deg + nNodes;          // [nNodes+1]
    int* cursor = rowptr + nNodes + 1;   // [nNodes]
    int* bsum   = cursor + nNodes;       // [128]
    int* eidx   = bsum + 128;            // [nEdges]

    k_zero_i32<<<256, 256, 0, stream>>>(deg, nNodes);
    k_hist    <<<2048, 256, 0, stream>>>(dst, deg, nEdges);
    k_scan1   <<<NB, SCAN_B, 0, stream>>>(deg, rowptr, bsum, nNodes);
    k_scan2   <<<1, 128, 0, stream>>>(bsum, NB);
    k_scan3   <<<(nNodes + 255) / 256, 256, 0, stream>>>(rowptr, bsum, cursor,
                                                         nNodes, nEdges);
    k_fill    <<<2048, 256, 0, stream>>>(src, dst, cursor, eidx, nEdges);
    k_agg_mean<<<2048, 256, 0, stream>>>(feat, rowptr, eidx, out, nNodes);
    k_transform<<<2048, 256, 0, stream>>>(feat, Ws, Wn, bias, out, nNodes);
}